// Round 9
// baseline (327.566 us; speedup 1.0000x reference)
//
#include <hip/hip_runtime.h>

// B=2, S=8192, D=1024, H=16, DK=DV=64, W=Bq=128, nb=64.
// Pipeline: prep ; gemm_qkv (fused N=3072) ; swa ; gemm_bt (out proj).
// R8: swa row-sums via MFMA (ls += mfma(pa, ones)) — removes 192 VALU adds/wave +
//     epilogue shuffle-reduce; denominator now sums the same bf16 P as the PV
//     numerator. GEMM core stays R3 (best measured: 101.5us, 44% MfmaUtil).
// ws: xb 33.5 + WqkvT 6.3 + WoT 2.1 + qh 33.5 + kh 33.5 + vT2 33.5 + ctx 33.5 = 176MB

typedef __bf16 bf16_t;
typedef bf16_t bf16x8 __attribute__((ext_vector_type(8)));
typedef bf16_t bf16x4 __attribute__((ext_vector_type(4)));
typedef float f32x4 __attribute__((ext_vector_type(4)));

#define CEXP 0.18033688011112042f  // 0.125 * log2(e), folded into WqT in prep

__device__ __forceinline__ f32x4 mfma16(bf16x8 a, bf16x8 b, f32x4 c) {
  return __builtin_amdgcn_mfma_f32_16x16x32_bf16(a, b, c, 0, 0, 0);
}

#define GLL16(gptr, lptr)                                                     \
  __builtin_amdgcn_global_load_lds(                                           \
      (__attribute__((address_space(1))) void*)(gptr),                        \
      (__attribute__((address_space(3))) void*)(lptr), 16, 0, 0)

// ---------------- prep: x fp32->bf16 (blocks 0..8191) + weight transpose (8192..12287)
// z==0 (Wq) tile values are scaled by CEXP so the QK^T output arrives pre-scaled
// for exp2 (saves 64 v_mul per chunk per wave in swa).
__global__ __launch_bounds__(256) void prep(const float* __restrict__ x,
                                            const float* __restrict__ W0,
                                            const float* __restrict__ W1,
                                            const float* __restrict__ W2,
                                            const float* __restrict__ W3,
                                            bf16_t* __restrict__ xb,
                                            bf16_t* T0, bf16_t* T1,
                                            bf16_t* T2, bf16_t* T3) {
  __shared__ float tile[32][33];
  const int t = threadIdx.x;
  if (blockIdx.x < 8192) {
    int i = blockIdx.x * 256 + t;
    f32x4 a = *(const f32x4*)&x[(size_t)i * 8];
    f32x4 b = *(const f32x4*)&x[(size_t)i * 8 + 4];
    bf16x8 o;
#pragma unroll
    for (int j = 0; j < 4; ++j) { o[j] = (bf16_t)a[j]; o[4 + j] = (bf16_t)b[j]; }
    *(bf16x8*)&xb[(size_t)i * 8] = o;
    return;
  }
  int wb = blockIdx.x - 8192;
  int z = wb >> 10, rem = wb & 1023;
  int bx = rem & 31, by = rem >> 5;
  const float* W; bf16_t* T;
  switch (z) {
    case 0: W = W0; T = T0; break;
    case 1: W = W1; T = T1; break;
    case 2: W = W2; T = T2; break;
    default: W = W3; T = T3; break;
  }
  const float s = (z == 0) ? CEXP : 1.0f;
  int tx = t & 31, ty = t >> 5;
  int xc = bx * 32 + tx;
  int y0 = by * 32;
#pragma unroll
  for (int i = ty; i < 32; i += 8) tile[i][tx] = W[(size_t)(y0 + i) * 1024 + xc];
  __syncthreads();
  int xo = y0 + tx;
  int yo = bx * 32;
#pragma unroll
  for (int i = ty; i < 32; i += 8)
    T[(size_t)(yo + i) * 1024 + xo] = (bf16_t)(tile[tx][i] * s);
}

// ---------------- 256x256 8-wave interleaved GEMM core (K=1024, BK=32) --------------
// R3 core (best measured). LDS: 4-slot ring of [256r][32c] planes.
// Swizzle (both sides): 16B-chunk cc' = cc ^ ((row>>1)&3) (measured: 0 conflicts).
// Per tile tk (2 barriers): phase A MFMA x16 w/ embedded afB read ; mid {GLL x4,
// vmcnt(4)} ; barrier ; phase B MFMA x16 w/ embedded next-tile bq2+afA reads ; barrier.
__device__ __forceinline__ void gemm256_loop(const bf16_t* __restrict__ A,
                                             const bf16_t* __restrict__ Bt,
                                             int m0, int n0,
                                             bf16_t (*As)[8192],
                                             bf16_t (*Bs)[8192],
                                             f32x4 acc[8][4]) {
  const int K = 1024, NT = 32;
  const int t = threadIdx.x, l = t & 63, w = t >> 6;
  const int fr = l & 15, quad = l >> 4;
  const int wm = w >> 2, wn = w & 3;
  const int srow = w * 16 + (l >> 2);
  const int scol = ((l & 3) ^ ((l >> 3) & 3)) << 3;
  const bf16_t* Asrc = A + (size_t)(m0 + srow) * K + scol;
  const bf16_t* Bsrc = Bt + (size_t)(n0 + srow) * K + scol;
  const size_t cstep = (size_t)128 * K;
  const int sdst = w * 512 + l * 8;   // lane-contiguous LDS dest (elems)
  const int rdoff = fr * 32 + ((quad ^ ((fr >> 1) & 3)) << 3);
  const int abase = wm * 4096 + rdoff;  // (wm*128)*32
  const int bbase = wn * 2048 + rdoff;  // (wn*64)*32

  // prologue: stage tiles 0 and 1, gate tile 0, preload its fragments
#pragma unroll
  for (int tt = 0; tt < 2; ++tt) {
    GLL16(Asrc + tt * 32, &As[tt][sdst]);
    GLL16(Asrc + cstep + tt * 32, &As[tt][4096 + sdst]);
    GLL16(Bsrc + tt * 32, &Bs[tt][sdst]);
    GLL16(Bsrc + cstep + tt * 32, &Bs[tt][4096 + sdst]);
  }
  asm volatile("s_waitcnt vmcnt(4)" ::: "memory");
  __builtin_amdgcn_s_barrier();

  bf16x8 bq[4], bq2[4], afA[4], afB[4];
#pragma unroll
  for (int j = 0; j < 4; ++j) bq[j] = *(const bf16x8*)&Bs[0][bbase + j * 512];
#pragma unroll
  for (int i = 0; i < 4; ++i) afA[i] = *(const bf16x8*)&As[0][abase + i * 512];

#pragma unroll 4
  for (int tk = 0; tk < NT; ++tk) {
    const bf16_t* Ap = As[tk & 3];
    // ---- phase A: MFMA m0..3, embedded read of afB (same slot) ----
    __builtin_amdgcn_s_setprio(1);
#pragma unroll
    for (int i = 0; i < 4; ++i) afB[i] = *(const bf16x8*)&Ap[abase + (4 + i) * 512];
#pragma unroll
    for (int i = 0; i < 4; ++i)
#pragma unroll
      for (int j = 0; j < 4; ++j) acc[i][j] = mfma16(afA[i], bq[j], acc[i][j]);
    __builtin_amdgcn_s_setprio(0);
    // ---- mid window: stage tk+2, counted gate so tile tk+1 is resident ----
    if (tk + 2 < NT) {
      const int s2 = (tk + 2) & 3;
      GLL16(Asrc + (tk + 2) * 32, &As[s2][sdst]);
      GLL16(Asrc + cstep + (tk + 2) * 32, &As[s2][4096 + sdst]);
      GLL16(Bsrc + (tk + 2) * 32, &Bs[s2][sdst]);
      GLL16(Bsrc + cstep + (tk + 2) * 32, &Bs[s2][4096 + sdst]);
      asm volatile("s_waitcnt vmcnt(4)" ::: "memory");
    } else {
      asm volatile("s_waitcnt vmcnt(0)" ::: "memory");
    }
    __builtin_amdgcn_s_barrier();
    // ---- phase B: MFMA m4..7, embedded reads of next tile's bq2 + afA ----
    __builtin_amdgcn_s_setprio(1);
    if (tk + 1 < NT) {
      const bf16_t* An = As[(tk + 1) & 3];
      const bf16_t* Bn = Bs[(tk + 1) & 3];
#pragma unroll
      for (int j = 0; j < 4; ++j) bq2[j] = *(const bf16x8*)&Bn[bbase + j * 512];
#pragma unroll
      for (int i = 0; i < 4; ++i) afA[i] = *(const bf16x8*)&An[abase + i * 512];
    }
#pragma unroll
    for (int i = 0; i < 4; ++i)
#pragma unroll
      for (int j = 0; j < 4; ++j) acc[4 + i][j] = mfma16(afB[i], bq[j], acc[4 + i][j]);
    __builtin_amdgcn_s_setprio(0);
    __builtin_amdgcn_s_barrier();
#pragma unroll
    for (int j = 0; j < 4; ++j) bq[j] = bq2[j];
  }
}

// ---------------- fused QKV GEMM: xb[16384,1024] x WqkvT[3072,1024]^T -------------
// grid (12, 64) = 768 wgs; bijective XCD swizzle, m-band per XCD (A-panel L2 reuse).
__global__ __launch_bounds__(512, 2) void gemm_qkv(const bf16_t* __restrict__ A,
                                                   const bf16_t* __restrict__ Bt,
                                                   bf16_t* __restrict__ qh,
                                                   bf16_t* __restrict__ kh,
                                                   bf16_t* __restrict__ vT2) {
  __shared__ bf16_t As[4][8192];
  __shared__ bf16_t Bs[4][8192];
  const int id = blockIdx.y * 12 + blockIdx.x;
  const int swz = (id & 7) * 96 + (id >> 3);
  const int m0 = (swz / 12) << 8, n0 = (swz % 12) << 8;

  f32x4 acc[8][4] = {};
  gemm256_loop(A, Bt, m0, n0, As, Bs, acc);

  const int t = threadIdx.x, l = t & 63, w = t >> 6;
  const int fr = l & 15, quad = l >> 4;
  const int wm = w >> 2, wn = w & 3;
  const int colbase = n0 + wn * 64;      // 64-aligned -> single head per wave
  if (colbase < 2048) {
    bf16_t* dst = (colbase < 1024) ? qh : kh;
    const int cb = colbase & 1023;
#pragma unroll
    for (int i = 0; i < 8; ++i)
#pragma unroll
      for (int j = 0; j < 4; ++j) {
        int col = cb + j * 16 + fr;
        int h = col >> 6, dk = col & 63;
#pragma unroll
        for (int r = 0; r < 4; ++r) {
          int cm = m0 + wm * 128 + i * 16 + quad * 4 + r;
          int b = cm >> 13, s = cm & 8191;
          dst[((((size_t)(b * 16 + h) << 13) | s) << 6) | dk] = (bf16_t)acc[i][j][r];
        }
      }
  } else {
    const int cb = colbase - 2048;
#pragma unroll
    for (int i = 0; i < 8; ++i) {
      int s0 = m0 + wm * 128 + i * 16;
      int b = s0 >> 13, sblk = (s0 & 8191) >> 4;
#pragma unroll
      for (int j = 0; j < 4; ++j) {
        int col = cb + j * 16;
        int h = col >> 6, dv = (col & 63) + fr;
        bf16x4 pk;
#pragma unroll
        for (int r = 0; r < 4; ++r) pk[r] = (bf16_t)acc[i][j][r];
        *(bf16x4*)&vT2[((size_t)(b * 16 + h) * 512 + sblk) * 1024 + dv * 16 + quad * 4] = pk;
      }
    }
  }
}

// ---------------- out-proj GEMM: ctx[16384,1024] x WoT[1024,1024]^T -> fp32 -------
// grid (4, 64) = 256 wgs; same engine.
__global__ __launch_bounds__(512, 2) void gemm_bt(const bf16_t* __restrict__ A,
                                                  const bf16_t* __restrict__ Bt,
                                                  float* __restrict__ Cf) {
  __shared__ bf16_t As[4][8192];
  __shared__ bf16_t Bs[4][8192];
  const int id = blockIdx.y * 4 + blockIdx.x;
  const int swz = (id & 7) * 32 + (id >> 3);
  const int m0 = (swz >> 2) << 8, n0 = (swz & 3) << 8;

  f32x4 acc[8][4] = {};
  gemm256_loop(A, Bt, m0, n0, As, Bs, acc);

  const int t = threadIdx.x, l = t & 63, w = t >> 6;
  const int fr = l & 15, quad = l >> 4;
  const int wm = w >> 2, wn = w & 3;
#pragma unroll
  for (int i = 0; i < 8; ++i)
#pragma unroll
    for (int j = 0; j < 4; ++j)
#pragma unroll
      for (int r = 0; r < 4; ++r) {
        int cm = m0 + wm * 128 + i * 16 + quad * 4 + r;
        int cn = n0 + wn * 64 + j * 16 + fr;
        Cf[(size_t)cm * 1024 + cn] = acc[i][j][r];
      }
}

// ---------------- sliding-window attention ----------------
// qh/kh: [b*16+h][8192][64]; vT2: [b*16+h][512 sblk][64 dv][16 s].
// S^T = K Q^T form; P^T b64 stores; 2 barriers/chunk; K/V prefetched into VGPRs.
// Q arrives pre-scaled by CEXP (prep) -> p = exp2f(st) directly.
// Row sums via MFMA: ls[qt] += mfma(pa, ones) — D-layout row (quad*4+r) = q matches
// the O epilogue indexing, so no cross-lane reduce/redistribute is needed.
#define SKK 72    // K tile stride (64+8)
#define SVS 136   // Vs stride (128+8)
#define PST 136   // PsT stride (128+8)

__global__ __launch_bounds__(256, 3) void swa(const bf16_t* __restrict__ qh,
                                              const bf16_t* __restrict__ kh,
                                              const bf16_t* __restrict__ vT2,
                                              bf16_t* __restrict__ ctx) {
  __shared__ bf16_t Ks[128 * SKK];       // 18.4 KB [key][dk]
  __shared__ bf16_t Vs[64 * SVS];        // 17.4 KB [dv][key]
  __shared__ bf16_t PsT[4][16 * PST];    // 17.4 KB per-wave P^T [q16][key]

  const int t = threadIdx.x, lane = t & 63, w = t >> 6;
  const int n = blockIdx.x, h = blockIdx.y, b = blockIdx.z;
  const int fr = lane & 15, quad = lane >> 4, fk = quad << 3;
  const size_t bh = (size_t)(b * 16 + h);

  // Q fragments (B-operand: n=q=fr, k=dk=quad*8+j)
  bf16x8 aq[2][2];
  {
    const size_t qbase = (bh * 8192 + n * 128 + w * 32) * 64;
#pragma unroll
    for (int qt = 0; qt < 2; ++qt)
#pragma unroll
      for (int ks = 0; ks < 2; ++ks)
        aq[qt][ks] = *(const bf16x8*)&qh[qbase + (size_t)(qt * 16 + fr) * 64 + ks * 32 + fk];
  }

  bf16x8 ones;
#pragma unroll
  for (int j = 0; j < 8; ++j) ones[j] = (bf16_t)1.0f;

  bf16x8 kr[4], vr[4];
  auto loadKV = [&](int kn) {
#pragma unroll
    for (int it = 0; it < 4; ++it) {
      int c = it * 256 + t;
      kr[it] = *(const bf16x8*)&kh[(bh * 8192 + kn * 128 + (c >> 3)) * 64 + ((c & 7) << 3)];
      int sb = c >> 7, dv = (c & 127) >> 1, sh = c & 1;
      vr[it] = *(const bf16x8*)&vT2[(bh * 512 + kn * 8 + sb) * 1024 + dv * 16 + sh * 8];
    }
  };

  const int cbeg = (n == 0) ? 1 : 0;
  const int cend = (n == 63) ? 1 : 2;
  loadKV(n + cbeg - 1);

  f32x4 ls[2] = {};     // row sums via MFMA: ls[qt][r] = sum_k P[q=quad*4+r, k]
  f32x4 o[2][4] = {};   // C-layout O[q][dv]: col dv = fr, row q = quad*4+r (+16*qt)

  for (int ch = cbeg; ch <= cend; ++ch) {
    __syncthreads();   // waves done reading Ks/Vs of prev chunk; drains prefetch vmcnt
#pragma unroll
    for (int it = 0; it < 4; ++it) {
      int c = it * 256 + t;
      *(bf16x8*)&Ks[(c >> 3) * SKK + ((c & 7) << 3)] = kr[it];
      int sb = c >> 7, dv = (c & 127) >> 1, sh = c & 1;
      *(bf16x8*)&Vs[dv * SVS + sb * 16 + sh * 8] = vr[it];
    }
    __syncthreads();   // cheap: lgkm only, VM queue empty
    if (ch < cend) loadKV(n + ch);   // next chunk's loads fly during compute

#pragma unroll
    for (int qt = 0; qt < 2; ++qt) {
      const int lo = (ch == 0) ? 2 * w + qt : 0;
      const int hi = (ch == 2) ? 2 * w + qt : 7;

      // S^T tiles: D[key][q], A = K (m=key=fr, k=dk), B = Q
      f32x4 st[8];
      __builtin_amdgcn_s_setprio(1);
#pragma unroll
      for (int kt = 0; kt < 8; ++kt) {
        if (kt < lo || kt > hi) continue;
        bf16x8 k0 = *(const bf16x8*)&Ks[(kt * 16 + fr) * SKK + fk];
        bf16x8 k1 = *(const bf16x8*)&Ks[(kt * 16 + fr) * SKK + 32 + fk];
        st[kt] = mfma16(k1, aq[qt][1], mfma16(k0, aq[qt][0], (f32x4){0.f, 0.f, 0.f, 0.f}));
      }
      __builtin_amdgcn_s_setprio(0);

      // exp + diagonal mask + P^T write (b64: 4 consecutive keys per lane)
#pragma unroll
      for (int kt = 0; kt < 8; ++kt) {
        if (kt < lo || kt > hi) continue;
        const bool dL = (ch == 0) && (kt == lo);
        const bool dR = (ch == 2) && (kt == hi);
        bf16x4 pk;
#pragma unroll
        for (int r = 0; r < 4; ++r) {
          float p = exp2f(st[kt][r]);          // scale pre-folded into Q
          int kl = quad * 4 + r;     // key within tile; q within tile = fr
          if (dL) p = (kl >= fr) ? p : 0.f;
          if (dR) p = (kl <= fr) ? p : 0.f;
          pk[r] = (bf16_t)p;
        }
        *(bf16x4*)&PsT[w][fr * PST + kt * 16 + quad * 4] = pk;
      }
      // zero-fill the single read-but-unwritten tile on edge chunks
      if ((ch == 0) && (lo & 1)) {
        bf16x4 zz; zz[0] = zz[1] = zz[2] = zz[3] = (bf16_t)0.f;
        *(bf16x4*)&PsT[w][fr * PST + (lo - 1) * 16 + quad * 4] = zz;
      }
      if ((ch == 2) && !(hi & 1)) {
        bf16x4 zz; zz[0] = zz[1] = zz[2] = zz[3] = (bf16_t)0.f;
        *(bf16x4*)&PsT[w][fr * PST + (hi + 1) * 16 + quad * 4] = zz;
      }

      // O += P V  (A = P [m=q=fr, k=key], B = V [n=dv=fr, k=key]); ls += P . 1
      const int pl = lo >> 1, ph = hi >> 1;
      __builtin_amdgcn_s_setprio(1);
#pragma unroll
      for (int ks = 0; ks < 4; ++ks) {
        if (ks < pl || ks > ph) continue;
        bf16x8 pa = *(const bf16x8*)&PsT[w][fr * PST + ks * 32 + fk];
        ls[qt] = mfma16(pa, ones, ls[qt]);
#pragma unroll
        for (int dt = 0; dt < 4; ++dt) {
          bf16x8 bv = *(const bf16x8*)&Vs[(dt * 16 + fr) * SVS + ks * 32 + fk];
          o[qt][dt] = mfma16(pa, bv, o[qt][dt]);
        }
      }
      __builtin_amdgcn_s_setprio(0);
    }
  }

  // epilogue: rcp of per-row sums (already in the right lane/register slots)
#pragma unroll
  for (int qt = 0; qt < 2; ++qt) {
    f32x4 rl;
#pragma unroll
    for (int r = 0; r < 4; ++r) rl[r] = __builtin_amdgcn_rcpf(ls[qt][r]);
#pragma unroll
    for (int dt = 0; dt < 4; ++dt)
#pragma unroll
      for (int r = 0; r < 4; ++r) {
        float ov = o[qt][dt][r] * rl[r];
        int srow = n * 128 + w * 32 + qt * 16 + quad * 4 + r;
        ctx[((size_t)b * 8192 + srow) * 1024 + h * 64 + dt * 16 + fr] = (bf16_t)ov;
      }
  }
}

// ---------------- launch ----------------
extern "C" void kernel_launch(void* const* d_in, const int* in_sizes, int n_in,
                              void* d_out, int out_size, void* d_ws, size_t ws_size,
                              hipStream_t stream) {
  const float* x  = (const float*)d_in[0];
  const float* Wq = (const float*)d_in[1];
  const float* Wk = (const float*)d_in[2];
  const float* Wv = (const float*)d_in[3];
  const float* Wo = (const float*)d_in[4];
  float* out = (float*)d_out;

  char* p = (char*)d_ws;
  bf16_t* xb    = (bf16_t*)p; p += (size_t)16384 * 1024 * 2;
  bf16_t* WqkvT = (bf16_t*)p; p += (size_t)3 * 1024 * 1024 * 2;
  bf16_t* WoT   = (bf16_t*)p; p += (size_t)1024 * 1024 * 2;
  bf16_t* qhb   = (bf16_t*)p; p += (size_t)16384 * 1024 * 2;
  bf16_t* khb   = (bf16_t*)p; p += (size_t)16384 * 1024 * 2;
  bf16_t* vT2   = (bf16_t*)p; p += (size_t)16384 * 1024 * 2;
  bf16_t* ctx   = (bf16_t*)p; p += (size_t)16384 * 1024 * 2;

  prep<<<12288, 256, 0, stream>>>(x, Wq, Wk, Wv, Wo, xb, WqkvT,
                                  WqkvT + (size_t)1024 * 1024,
                                  WqkvT + (size_t)2 * 1024 * 1024, WoT);
  gemm_qkv<<<dim3(12, 64), 512, 0, stream>>>(xb, WqkvT, qhb, khb, vT2);
  swa<<<dim3(64, 16, 2), 256, 0, stream>>>(qhb, khb, vT2, ctx);
  gemm_bt<<<dim3(4, 64), 512, 0, stream>>>(ctx, WoT, out);
}

// Round 10
// 324.311 us; speedup vs baseline: 1.0100x; 1.0100x over previous
//
#include <hip/hip_runtime.h>

// B=2, S=8192, D=1024, H=16, DK=DV=64, W=Bq=128, nb=64.
// Pipeline: prep ; gemm_qkv (fused N=3072) ; swa ; gemm_bt (out proj).
// R9: swa XCD-cluster swizzle — each XCD gets 256 consecutive blocks = 4 full (b,h)
//     slices, so the 3x K/V chunk reuse across neighboring n-blocks becomes L2-local
//     (slice K+V = 2MB < 4MB per-XCD L2). GEMM core stays R3; swa math stays R8.
// ws: xb 33.5 + WqkvT 6.3 + WoT 2.1 + qh 33.5 + kh 33.5 + vT2 33.5 + ctx 33.5 = 176MB

typedef __bf16 bf16_t;
typedef bf16_t bf16x8 __attribute__((ext_vector_type(8)));
typedef bf16_t bf16x4 __attribute__((ext_vector_type(4)));
typedef float f32x4 __attribute__((ext_vector_type(4)));

#define CEXP 0.18033688011112042f  // 0.125 * log2(e), folded into WqT in prep

__device__ __forceinline__ f32x4 mfma16(bf16x8 a, bf16x8 b, f32x4 c) {
  return __builtin_amdgcn_mfma_f32_16x16x32_bf16(a, b, c, 0, 0, 0);
}

#define GLL16(gptr, lptr)                                                     \
  __builtin_amdgcn_global_load_lds(                                           \
      (__attribute__((address_space(1))) void*)(gptr),                        \
      (__attribute__((address_space(3))) void*)(lptr), 16, 0, 0)

// ---------------- prep: x fp32->bf16 (blocks 0..8191) + weight transpose (8192..12287)
// z==0 (Wq) tile values are scaled by CEXP so the QK^T output arrives pre-scaled
// for exp2 (saves 64 v_mul per chunk per wave in swa).
__global__ __launch_bounds__(256) void prep(const float* __restrict__ x,
                                            const float* __restrict__ W0,
                                            const float* __restrict__ W1,
                                            const float* __restrict__ W2,
                                            const float* __restrict__ W3,
                                            bf16_t* __restrict__ xb,
                                            bf16_t* T0, bf16_t* T1,
                                            bf16_t* T2, bf16_t* T3) {
  __shared__ float tile[32][33];
  const int t = threadIdx.x;
  if (blockIdx.x < 8192) {
    int i = blockIdx.x * 256 + t;
    f32x4 a = *(const f32x4*)&x[(size_t)i * 8];
    f32x4 b = *(const f32x4*)&x[(size_t)i * 8 + 4];
    bf16x8 o;
#pragma unroll
    for (int j = 0; j < 4; ++j) { o[j] = (bf16_t)a[j]; o[4 + j] = (bf16_t)b[j]; }
    *(bf16x8*)&xb[(size_t)i * 8] = o;
    return;
  }
  int wb = blockIdx.x - 8192;
  int z = wb >> 10, rem = wb & 1023;
  int bx = rem & 31, by = rem >> 5;
  const float* W; bf16_t* T;
  switch (z) {
    case 0: W = W0; T = T0; break;
    case 1: W = W1; T = T1; break;
    case 2: W = W2; T = T2; break;
    default: W = W3; T = T3; break;
  }
  const float s = (z == 0) ? CEXP : 1.0f;
  int tx = t & 31, ty = t >> 5;
  int xc = bx * 32 + tx;
  int y0 = by * 32;
#pragma unroll
  for (int i = ty; i < 32; i += 8) tile[i][tx] = W[(size_t)(y0 + i) * 1024 + xc];
  __syncthreads();
  int xo = y0 + tx;
  int yo = bx * 32;
#pragma unroll
  for (int i = ty; i < 32; i += 8)
    T[(size_t)(yo + i) * 1024 + xo] = (bf16_t)(tile[tx][i] * s);
}

// ---------------- 256x256 8-wave interleaved GEMM core (K=1024, BK=32) --------------
// R3 core (best measured). LDS: 4-slot ring of [256r][32c] planes.
// Swizzle (both sides): 16B-chunk cc' = cc ^ ((row>>1)&3) (measured: 0 conflicts).
// Per tile tk (2 barriers): phase A MFMA x16 w/ embedded afB read ; mid {GLL x4,
// vmcnt(4)} ; barrier ; phase B MFMA x16 w/ embedded next-tile bq2+afA reads ; barrier.
__device__ __forceinline__ void gemm256_loop(const bf16_t* __restrict__ A,
                                             const bf16_t* __restrict__ Bt,
                                             int m0, int n0,
                                             bf16_t (*As)[8192],
                                             bf16_t (*Bs)[8192],
                                             f32x4 acc[8][4]) {
  const int K = 1024, NT = 32;
  const int t = threadIdx.x, l = t & 63, w = t >> 6;
  const int fr = l & 15, quad = l >> 4;
  const int wm = w >> 2, wn = w & 3;
  const int srow = w * 16 + (l >> 2);
  const int scol = ((l & 3) ^ ((l >> 3) & 3)) << 3;
  const bf16_t* Asrc = A + (size_t)(m0 + srow) * K + scol;
  const bf16_t* Bsrc = Bt + (size_t)(n0 + srow) * K + scol;
  const size_t cstep = (size_t)128 * K;
  const int sdst = w * 512 + l * 8;   // lane-contiguous LDS dest (elems)
  const int rdoff = fr * 32 + ((quad ^ ((fr >> 1) & 3)) << 3);
  const int abase = wm * 4096 + rdoff;  // (wm*128)*32
  const int bbase = wn * 2048 + rdoff;  // (wn*64)*32

  // prologue: stage tiles 0 and 1, gate tile 0, preload its fragments
#pragma unroll
  for (int tt = 0; tt < 2; ++tt) {
    GLL16(Asrc + tt * 32, &As[tt][sdst]);
    GLL16(Asrc + cstep + tt * 32, &As[tt][4096 + sdst]);
    GLL16(Bsrc + tt * 32, &Bs[tt][sdst]);
    GLL16(Bsrc + cstep + tt * 32, &Bs[tt][4096 + sdst]);
  }
  asm volatile("s_waitcnt vmcnt(4)" ::: "memory");
  __builtin_amdgcn_s_barrier();

  bf16x8 bq[4], bq2[4], afA[4], afB[4];
#pragma unroll
  for (int j = 0; j < 4; ++j) bq[j] = *(const bf16x8*)&Bs[0][bbase + j * 512];
#pragma unroll
  for (int i = 0; i < 4; ++i) afA[i] = *(const bf16x8*)&As[0][abase + i * 512];

#pragma unroll 4
  for (int tk = 0; tk < NT; ++tk) {
    const bf16_t* Ap = As[tk & 3];
    // ---- phase A: MFMA m0..3, embedded read of afB (same slot) ----
    __builtin_amdgcn_s_setprio(1);
#pragma unroll
    for (int i = 0; i < 4; ++i) afB[i] = *(const bf16x8*)&Ap[abase + (4 + i) * 512];
#pragma unroll
    for (int i = 0; i < 4; ++i)
#pragma unroll
      for (int j = 0; j < 4; ++j) acc[i][j] = mfma16(afA[i], bq[j], acc[i][j]);
    __builtin_amdgcn_s_setprio(0);
    // ---- mid window: stage tk+2, counted gate so tile tk+1 is resident ----
    if (tk + 2 < NT) {
      const int s2 = (tk + 2) & 3;
      GLL16(Asrc + (tk + 2) * 32, &As[s2][sdst]);
      GLL16(Asrc + cstep + (tk + 2) * 32, &As[s2][4096 + sdst]);
      GLL16(Bsrc + (tk + 2) * 32, &Bs[s2][sdst]);
      GLL16(Bsrc + cstep + (tk + 2) * 32, &Bs[s2][4096 + sdst]);
      asm volatile("s_waitcnt vmcnt(4)" ::: "memory");
    } else {
      asm volatile("s_waitcnt vmcnt(0)" ::: "memory");
    }
    __builtin_amdgcn_s_barrier();
    // ---- phase B: MFMA m4..7, embedded reads of next tile's bq2 + afA ----
    __builtin_amdgcn_s_setprio(1);
    if (tk + 1 < NT) {
      const bf16_t* An = As[(tk + 1) & 3];
      const bf16_t* Bn = Bs[(tk + 1) & 3];
#pragma unroll
      for (int j = 0; j < 4; ++j) bq2[j] = *(const bf16x8*)&Bn[bbase + j * 512];
#pragma unroll
      for (int i = 0; i < 4; ++i) afA[i] = *(const bf16x8*)&An[abase + i * 512];
    }
#pragma unroll
    for (int i = 0; i < 4; ++i)
#pragma unroll
      for (int j = 0; j < 4; ++j) acc[4 + i][j] = mfma16(afB[i], bq[j], acc[4 + i][j]);
    __builtin_amdgcn_s_setprio(0);
    __builtin_amdgcn_s_barrier();
#pragma unroll
    for (int j = 0; j < 4; ++j) bq[j] = bq2[j];
  }
}

// ---------------- fused QKV GEMM: xb[16384,1024] x WqkvT[3072,1024]^T -------------
// grid (12, 64) = 768 wgs; bijective XCD swizzle, m-band per XCD (A-panel L2 reuse).
__global__ __launch_bounds__(512, 2) void gemm_qkv(const bf16_t* __restrict__ A,
                                                   const bf16_t* __restrict__ Bt,
                                                   bf16_t* __restrict__ qh,
                                                   bf16_t* __restrict__ kh,
                                                   bf16_t* __restrict__ vT2) {
  __shared__ bf16_t As[4][8192];
  __shared__ bf16_t Bs[4][8192];
  const int id = blockIdx.y * 12 + blockIdx.x;
  const int swz = (id & 7) * 96 + (id >> 3);
  const int m0 = (swz / 12) << 8, n0 = (swz % 12) << 8;

  f32x4 acc[8][4] = {};
  gemm256_loop(A, Bt, m0, n0, As, Bs, acc);

  const int t = threadIdx.x, l = t & 63, w = t >> 6;
  const int fr = l & 15, quad = l >> 4;
  const int wm = w >> 2, wn = w & 3;
  const int colbase = n0 + wn * 64;      // 64-aligned -> single head per wave
  if (colbase < 2048) {
    bf16_t* dst = (colbase < 1024) ? qh : kh;
    const int cb = colbase & 1023;
#pragma unroll
    for (int i = 0; i < 8; ++i)
#pragma unroll
      for (int j = 0; j < 4; ++j) {
        int col = cb + j * 16 + fr;
        int h = col >> 6, dk = col & 63;
#pragma unroll
        for (int r = 0; r < 4; ++r) {
          int cm = m0 + wm * 128 + i * 16 + quad * 4 + r;
          int b = cm >> 13, s = cm & 8191;
          dst[((((size_t)(b * 16 + h) << 13) | s) << 6) | dk] = (bf16_t)acc[i][j][r];
        }
      }
  } else {
    const int cb = colbase - 2048;
#pragma unroll
    for (int i = 0; i < 8; ++i) {
      int s0 = m0 + wm * 128 + i * 16;
      int b = s0 >> 13, sblk = (s0 & 8191) >> 4;
#pragma unroll
      for (int j = 0; j < 4; ++j) {
        int col = cb + j * 16;
        int h = col >> 6, dv = (col & 63) + fr;
        bf16x4 pk;
#pragma unroll
        for (int r = 0; r < 4; ++r) pk[r] = (bf16_t)acc[i][j][r];
        *(bf16x4*)&vT2[((size_t)(b * 16 + h) * 512 + sblk) * 1024 + dv * 16 + quad * 4] = pk;
      }
    }
  }
}

// ---------------- out-proj GEMM: ctx[16384,1024] x WoT[1024,1024]^T -> fp32 -------
// grid (4, 64) = 256 wgs; same engine.
__global__ __launch_bounds__(512, 2) void gemm_bt(const bf16_t* __restrict__ A,
                                                  const bf16_t* __restrict__ Bt,
                                                  float* __restrict__ Cf) {
  __shared__ bf16_t As[4][8192];
  __shared__ bf16_t Bs[4][8192];
  const int id = blockIdx.y * 4 + blockIdx.x;
  const int swz = (id & 7) * 32 + (id >> 3);
  const int m0 = (swz >> 2) << 8, n0 = (swz & 3) << 8;

  f32x4 acc[8][4] = {};
  gemm256_loop(A, Bt, m0, n0, As, Bs, acc);

  const int t = threadIdx.x, l = t & 63, w = t >> 6;
  const int fr = l & 15, quad = l >> 4;
  const int wm = w >> 2, wn = w & 3;
#pragma unroll
  for (int i = 0; i < 8; ++i)
#pragma unroll
    for (int j = 0; j < 4; ++j)
#pragma unroll
      for (int r = 0; r < 4; ++r) {
        int cm = m0 + wm * 128 + i * 16 + quad * 4 + r;
        int cn = n0 + wn * 64 + j * 16 + fr;
        Cf[(size_t)cm * 1024 + cn] = acc[i][j][r];
      }
}

// ---------------- sliding-window attention ----------------
// qh/kh: [b*16+h][8192][64]; vT2: [b*16+h][512 sblk][64 dv][16 s].
// S^T = K Q^T form; P^T b64 stores; 2 barriers/chunk; K/V prefetched into VGPRs.
// Q arrives pre-scaled by CEXP (prep) -> p = exp2f(st) directly.
// Row sums via MFMA (R8). R9: XCD-cluster block swizzle — 256 consecutive content
// blocks (= 4 full bh slices) per XCD so neighbor-block K/V reuse is L2-local.
#define SKK 72    // K tile stride (64+8)
#define SVS 136   // Vs stride (128+8)
#define PST 136   // PsT stride (128+8)

__global__ __launch_bounds__(256, 3) void swa(const bf16_t* __restrict__ qh,
                                              const bf16_t* __restrict__ kh,
                                              const bf16_t* __restrict__ vT2,
                                              bf16_t* __restrict__ ctx) {
  __shared__ bf16_t Ks[128 * SKK];       // 18.4 KB [key][dk]
  __shared__ bf16_t Vs[64 * SVS];        // 17.4 KB [dv][key]
  __shared__ bf16_t PsT[4][16 * PST];    // 17.4 KB per-wave P^T [q16][key]

  const int t = threadIdx.x, lane = t & 63, w = t >> 6;
  // XCD-cluster swizzle: hardware linear id L -> content id swz, chunk 256/XCD.
  const int L = (blockIdx.z * 16 + blockIdx.y) * 64 + blockIdx.x;
  const int swz = (L & 7) * 256 + (L >> 3);
  const int n = swz & 63, bhid = swz >> 6;
  const int h = bhid & 15, b = bhid >> 4;
  const int fr = lane & 15, quad = lane >> 4, fk = quad << 3;
  const size_t bh = (size_t)(b * 16 + h);

  // Q fragments (B-operand: n=q=fr, k=dk=quad*8+j)
  bf16x8 aq[2][2];
  {
    const size_t qbase = (bh * 8192 + n * 128 + w * 32) * 64;
#pragma unroll
    for (int qt = 0; qt < 2; ++qt)
#pragma unroll
      for (int ks = 0; ks < 2; ++ks)
        aq[qt][ks] = *(const bf16x8*)&qh[qbase + (size_t)(qt * 16 + fr) * 64 + ks * 32 + fk];
  }

  bf16x8 ones;
#pragma unroll
  for (int j = 0; j < 8; ++j) ones[j] = (bf16_t)1.0f;

  bf16x8 kr[4], vr[4];
  auto loadKV = [&](int kn) {
#pragma unroll
    for (int it = 0; it < 4; ++it) {
      int c = it * 256 + t;
      kr[it] = *(const bf16x8*)&kh[(bh * 8192 + kn * 128 + (c >> 3)) * 64 + ((c & 7) << 3)];
      int sb = c >> 7, dv = (c & 127) >> 1, sh = c & 1;
      vr[it] = *(const bf16x8*)&vT2[(bh * 512 + kn * 8 + sb) * 1024 + dv * 16 + sh * 8];
    }
  };

  const int cbeg = (n == 0) ? 1 : 0;
  const int cend = (n == 63) ? 1 : 2;
  loadKV(n + cbeg - 1);

  f32x4 ls[2] = {};     // row sums via MFMA: ls[qt][r] = sum_k P[q=quad*4+r, k]
  f32x4 o[2][4] = {};   // C-layout O[q][dv]: col dv = fr, row q = quad*4+r (+16*qt)

  for (int ch = cbeg; ch <= cend; ++ch) {
    __syncthreads();   // waves done reading Ks/Vs of prev chunk; drains prefetch vmcnt
#pragma unroll
    for (int it = 0; it < 4; ++it) {
      int c = it * 256 + t;
      *(bf16x8*)&Ks[(c >> 3) * SKK + ((c & 7) << 3)] = kr[it];
      int sb = c >> 7, dv = (c & 127) >> 1, sh = c & 1;
      *(bf16x8*)&Vs[dv * SVS + sb * 16 + sh * 8] = vr[it];
    }
    __syncthreads();   // cheap: lgkm only, VM queue empty
    if (ch < cend) loadKV(n + ch);   // next chunk's loads fly during compute

#pragma unroll
    for (int qt = 0; qt < 2; ++qt) {
      const int lo = (ch == 0) ? 2 * w + qt : 0;
      const int hi = (ch == 2) ? 2 * w + qt : 7;

      // S^T tiles: D[key][q], A = K (m=key=fr, k=dk), B = Q
      f32x4 st[8];
      __builtin_amdgcn_s_setprio(1);
#pragma unroll
      for (int kt = 0; kt < 8; ++kt) {
        if (kt < lo || kt > hi) continue;
        bf16x8 k0 = *(const bf16x8*)&Ks[(kt * 16 + fr) * SKK + fk];
        bf16x8 k1 = *(const bf16x8*)&Ks[(kt * 16 + fr) * SKK + 32 + fk];
        st[kt] = mfma16(k1, aq[qt][1], mfma16(k0, aq[qt][0], (f32x4){0.f, 0.f, 0.f, 0.f}));
      }
      __builtin_amdgcn_s_setprio(0);

      // exp + diagonal mask + P^T write (b64: 4 consecutive keys per lane)
#pragma unroll
      for (int kt = 0; kt < 8; ++kt) {
        if (kt < lo || kt > hi) continue;
        const bool dL = (ch == 0) && (kt == lo);
        const bool dR = (ch == 2) && (kt == hi);
        bf16x4 pk;
#pragma unroll
        for (int r = 0; r < 4; ++r) {
          float p = exp2f(st[kt][r]);          // scale pre-folded into Q
          int kl = quad * 4 + r;     // key within tile; q within tile = fr
          if (dL) p = (kl >= fr) ? p : 0.f;
          if (dR) p = (kl <= fr) ? p : 0.f;
          pk[r] = (bf16_t)p;
        }
        *(bf16x4*)&PsT[w][fr * PST + kt * 16 + quad * 4] = pk;
      }
      // zero-fill the single read-but-unwritten tile on edge chunks
      if ((ch == 0) && (lo & 1)) {
        bf16x4 zz; zz[0] = zz[1] = zz[2] = zz[3] = (bf16_t)0.f;
        *(bf16x4*)&PsT[w][fr * PST + (lo - 1) * 16 + quad * 4] = zz;
      }
      if ((ch == 2) && !(hi & 1)) {
        bf16x4 zz; zz[0] = zz[1] = zz[2] = zz[3] = (bf16_t)0.f;
        *(bf16x4*)&PsT[w][fr * PST + (hi + 1) * 16 + quad * 4] = zz;
      }

      // O += P V  (A = P [m=q=fr, k=key], B = V [n=dv=fr, k=key]); ls += P . 1
      const int pl = lo >> 1, ph = hi >> 1;
      __builtin_amdgcn_s_setprio(1);
#pragma unroll
      for (int ks = 0; ks < 4; ++ks) {
        if (ks < pl || ks > ph) continue;
        bf16x8 pa = *(const bf16x8*)&PsT[w][fr * PST + ks * 32 + fk];
        ls[qt] = mfma16(pa, ones, ls[qt]);
#pragma unroll
        for (int dt = 0; dt < 4; ++dt) {
          bf16x8 bv = *(const bf16x8*)&Vs[(dt * 16 + fr) * SVS + ks * 32 + fk];
          o[qt][dt] = mfma16(pa, bv, o[qt][dt]);
        }
      }
      __builtin_amdgcn_s_setprio(0);
    }
  }

  // epilogue: rcp of per-row sums (already in the right lane/register slots)
#pragma unroll
  for (int qt = 0; qt < 2; ++qt) {
    f32x4 rl;
#pragma unroll
    for (int r = 0; r < 4; ++r) rl[r] = __builtin_amdgcn_rcpf(ls[qt][r]);
#pragma unroll
    for (int dt = 0; dt < 4; ++dt)
#pragma unroll
      for (int r = 0; r < 4; ++r) {
        float ov = o[qt][dt][r] * rl[r];
        int srow = n * 128 + w * 32 + qt * 16 + quad * 4 + r;
        ctx[((size_t)b * 8192 + srow) * 1024 + h * 64 + dt * 16 + fr] = (bf16_t)ov;
      }
  }
}

// ---------------- launch ----------------
extern "C" void kernel_launch(void* const* d_in, const int* in_sizes, int n_in,
                              void* d_out, int out_size, void* d_ws, size_t ws_size,
                              hipStream_t stream) {
  const float* x  = (const float*)d_in[0];
  const float* Wq = (const float*)d_in[1];
  const float* Wk = (const float*)d_in[2];
  const float* Wv = (const float*)d_in[3];
  const float* Wo = (const float*)d_in[4];
  float* out = (float*)d_out;

  char* p = (char*)d_ws;
  bf16_t* xb    = (bf16_t*)p; p += (size_t)16384 * 1024 * 2;
  bf16_t* WqkvT = (bf16_t*)p; p += (size_t)3 * 1024 * 1024 * 2;
  bf16_t* WoT   = (bf16_t*)p; p += (size_t)1024 * 1024 * 2;
  bf16_t* qhb   = (bf16_t*)p; p += (size_t)16384 * 1024 * 2;
  bf16_t* khb   = (bf16_t*)p; p += (size_t)16384 * 1024 * 2;
  bf16_t* vT2   = (bf16_t*)p; p += (size_t)16384 * 1024 * 2;
  bf16_t* ctx   = (bf16_t*)p; p += (size_t)16384 * 1024 * 2;

  prep<<<12288, 256, 0, stream>>>(x, Wq, Wk, Wv, Wo, xb, WqkvT,
                                  WqkvT + (size_t)1024 * 1024,
                                  WqkvT + (size_t)2 * 1024 * 1024, WoT);
  gemm_qkv<<<dim3(12, 64), 512, 0, stream>>>(xb, WqkvT, qhb, khb, vT2);
  swa<<<dim3(64, 16, 2), 256, 0, stream>>>(qhb, khb, vT2, ctx);
  gemm_bt<<<dim3(4, 64), 512, 0, stream>>>(ctx, WoT, out);
}